// Round 10
// baseline (147.404 us; speedup 1.0000x reference)
//
#include <hip/hip_runtime.h>
#include <hip/hip_bf16.h>

#define NN 1024

typedef __attribute__((ext_vector_type(8))) short short8;     // 8 x bf16 MFMA frag
typedef __attribute__((ext_vector_type(4))) short short4e;    // 4 x bf16 packed store
typedef __attribute__((ext_vector_type(4))) float floatx4;
typedef __attribute__((ext_vector_type(4))) int intx4;

static __device__ __forceinline__ short bfb(float x) {
    return (short)__bfloat16_as_ushort(__float2bfloat16(x));
}

// ================= K1: Wh GEMM (direct f32 W reads) + si/sj in-block + aux prep =================
// grid = 512 main (16 token-rows each) + 16 (pwb cast) + 128 (adj bitmask) = 656 blocks.
__global__ __launch_bounds__(256) void wh_kernel(
    const float* __restrict__ h, const float* __restrict__ W,
    const float* __restrict__ a1, const float* __restrict__ a2,
    const float* __restrict__ proj_w, const int* __restrict__ adj,
    __hip_bfloat16* __restrict__ WhT,   // [B*H][64][NN] bf16
    float* __restrict__ si, float* __restrict__ sj,
    __hip_bfloat16* __restrict__ pwb,   // [256 o][256 k] bf16
    unsigned* __restrict__ adjm)        // [1024][32] bitmask
{
    int blk = blockIdx.x, t = threadIdx.x;

    if (blk >= 512) {                    // ---- aux prep (outputs consumed only by K2) ----
        if (blk < 528) {                 // pwb: f32 -> bf16 cast of proj_w
            size_t base = (size_t)(blk - 512) * 4096 + (size_t)t * 16;
            #pragma unroll
            for (int k = 0; k < 16; k += 4) {
                floatx4 v = *(const floatx4*)(proj_w + base + k);
                alignas(8) __hip_bfloat16 tmp[4];
                #pragma unroll
                for (int j = 0; j < 4; ++j) tmp[j] = __float2bfloat16(v[j]);
                *(short4e*)(pwb + base + k) = *(const short4e*)tmp;
            }
        } else {                         // adj bitmask
            int n = (blk - 528) * 8 + (t >> 5);
            int wd = t & 31;
            const int* arow = adj + (size_t)n * NN + wd * 32;
            unsigned bits = 0;
            #pragma unroll
            for (int j4 = 0; j4 < 8; ++j4) {
                intx4 v = *(const intx4*)(arow + j4 * 4);
                #pragma unroll
                for (int j = 0; j < 4; ++j) if (v[j] != 0) bits |= (1u << (j4 * 4 + j));
            }
            adjm[(size_t)n * 32 + wd] = bits;
        }
        return;
    }

    // ---- main: rows r0..r0+15, all 256 output cols (16 MFMA tiles, 4/wave) ----
    int w = t >> 6, l = t & 63;
    int rl = l & 15, q = l >> 4;
    int r0 = blk * 16;
    int bb = r0 >> 10;
    int n0 = r0 & 1023;

    __shared__ float redsi[4][4][16];   // [wave][head][row]
    __shared__ float redsj[4][4][16];

    // A-frags: A[m=rl][k=q*8+j] from h rows (f32 -> bf16 in regs)
    short8 af[8];
    const float* Arow = h + (size_t)(r0 + rl) * 256 + q * 8;
    #pragma unroll
    for (int k0 = 0; k0 < 8; ++k0) {
        floatx4 v0 = *(const floatx4*)(Arow + k0 * 32);
        floatx4 v1 = *(const floatx4*)(Arow + k0 * 32 + 4);
        short8 a;
        #pragma unroll
        for (int j = 0; j < 4; ++j) { a[j] = bfb(v0[j]); a[j + 4] = bfb(v1[j]); }
        af[k0] = a;
    }

    // score vectors indexed per head j: a[j][d], d = w*16+rl (this wave's d-slice)
    float a1v[4], a2v[4];
    #pragma unroll
    for (int j = 0; j < 4; ++j) {
        a1v[j] = a1[j * 64 + w * 16 + rl];
        a2v[j] = a2[j * 64 + w * 16 + rl];
    }

    #pragma unroll
    for (int j = 0; j < 4; ++j) {        // tile ct = w + 4j  ->  head j, d-slice w*16..+15
        int ct = w + j * 4;
        const float* Wb = W + (size_t)(ct >> 2) * 16384 + (ct & 3) * 16 + rl;
        floatx4 acc = {0.f, 0.f, 0.f, 0.f};
        #pragma unroll
        for (int k0 = 0; k0 < 8; ++k0) {
            short8 bfr;                  // B[k=q*8+jj][o-col=rl] from W[hh][k][d] (64B-coalesced over rl)
            #pragma unroll
            for (int jj = 0; jj < 8; ++jj)
                bfr[jj] = bfb(Wb[(size_t)(k0 * 32 + q * 8 + jj) * 64]);
            acc = __builtin_amdgcn_mfma_f32_16x16x32_bf16(af[k0], bfr, acc, 0, 0, 0);
        }

        // store WhT[bh][d][n] (bh = bb*4+j, d = w*16+rl, n = n0 + q*4 + i)
        alignas(8) __hip_bfloat16 tmp[4];
        #pragma unroll
        for (int i = 0; i < 4; ++i) tmp[i] = __float2bfloat16(acc[i]);
        *(short4e*)(WhT + ((size_t)(bb * 4 + j) * 64 + w * 16 + rl) * NN + n0 + q * 4) =
            *(const short4e*)tmp;

        // si/sj partials: reduce acc[i]*a over this wave's 16 d's (lanes sharing q)
        #pragma unroll
        for (int i = 0; i < 4; ++i) {
            float p1 = acc[i] * a1v[j];
            float p2 = acc[i] * a2v[j];
            #pragma unroll
            for (int off = 1; off < 16; off <<= 1) {
                p1 += __shfl_xor(p1, off, 64);
                p2 += __shfl_xor(p2, off, 64);
            }
            if (rl == 0) { redsi[w][j][q * 4 + i] = p1; redsj[w][j][q * 4 + i] = p2; }
        }
    }
    __syncthreads();

    if (w == 0) {                        // si: 4 heads x 16 rows
        int head = l >> 4, row = l & 15;
        float s = redsi[0][head][row] + redsi[1][head][row] + redsi[2][head][row] + redsi[3][head][row];
        si[(size_t)(bb * 4 + head) * NN + n0 + row] = s;
    } else if (w == 1) {
        int head = l >> 4, row = l & 15;
        float s = redsj[0][head][row] + redsj[1][head][row] + redsj[2][head][row] + redsj[3][head][row];
        sj[(size_t)(bb * 4 + head) * NN + n0 + row] = s;
    }
}

// ================= K2: fused attn (wave = head, barrier-free m-loop) + proj + LayerNorm =================
// grid = 512 blocks (16 token-rows each), 256 threads = 4 waves.
__global__ __launch_bounds__(256) void attn_proj_kernel(
    const unsigned* __restrict__ adjm,
    const __hip_bfloat16* __restrict__ WhT,
    const float* __restrict__ si, const float* __restrict__ sj,
    const __hip_bfloat16* __restrict__ pwb,
    const float* __restrict__ h,
    const float* __restrict__ proj_b, const float* __restrict__ gamma,
    const float* __restrict__ beta,
    float* __restrict__ out)
{
    int blk = blockIdx.x, t = threadIdx.x;
    int w = t >> 6, l = t & 63;
    int rl = l & 15, q = l >> 4;
    int b = blk >> 6, n0 = (blk & 63) * 16;
    int bh = b * 4 + w;                  // wave = head
    int r0 = blk * 16;                   // = b*1024 + n0

    __shared__ __align__(16) __hip_bfloat16 p_lds[4][16 * 136];   // per-wave p tile [16][128+8]
    __shared__ __align__(16) __hip_bfloat16 hm_stage[16][264];    // [row][256+8]
    __shared__ float rinvs[4][16];
    __shared__ float red[2][4][16];

    // score-role lane mapping: row r (16), m-window cg*32 (4)
    int r = l >> 2, cg = l & 3;
    float sii = si[(size_t)bh * NN + n0 + r];
    const float* sjr = sj + (size_t)bh * NN;
    const unsigned* amrow = adjm + (size_t)(n0 + r) * 32;

    __hip_bfloat16* pt = &p_lds[w][0];
    const __hip_bfloat16* Ab = pt + rl * 136 + q * 8;
    const __hip_bfloat16* Bbase = WhT + ((size_t)bh * 64 + rl) * NN + q * 8;

    float lsum = 0.f;
    floatx4 acc[4] = { {0,0,0,0}, {0,0,0,0}, {0,0,0,0}, {0,0,0,0} };

    for (int m0 = 0; m0 < NN; m0 += 128) {
        int mb = m0 + cg * 32;
        unsigned bits = amrow[mb >> 5];
        alignas(16) __hip_bfloat16 tmp[32];
        #pragma unroll
        for (int c4 = 0; c4 < 8; ++c4) {
            floatx4 s4 = *(const floatx4*)(sjr + mb + c4 * 4);
            #pragma unroll
            for (int k = 0; k < 4; ++k) {
                float x = sii + s4[k];
                x = x > 0.f ? x : 0.2f * x;                       // leaky_relu 0.2
                x = ((bits >> (c4 * 4 + k)) & 1u) ? x : -1e9f;    // mask (exp -> 0)
                float pv = __expf(x);
                lsum += pv;
                tmp[c4 * 4 + k] = __float2bfloat16(pv);
            }
        }
        {   // 64B write into this wave's private p tile (wave-synchronous LDS, no barrier)
            short8* dst = (short8*)(pt + r * 136 + cg * 32);
            const short8* srcv = (const short8*)tmp;
            dst[0] = srcv[0]; dst[1] = srcv[1]; dst[2] = srcv[2]; dst[3] = srcv[3];
        }
        #pragma unroll
        for (int ks = 0; ks < 4; ++ks) {
            short8 afr = *(const short8*)(Ab + ks * 32);
            #pragma unroll
            for (int dt = 0; dt < 4; ++dt) {
                short8 bfr = *(const short8*)(Bbase + (size_t)dt * 16 * NN + m0 + ks * 32);
                acc[dt] = __builtin_amdgcn_mfma_f32_16x16x32_bf16(afr, bfr, acc[dt], 0, 0, 0);
            }
        }
    }

    // row sums (4 lanes share a row) -> rinv
    lsum += __shfl_xor(lsum, 1, 64);
    lsum += __shfl_xor(lsum, 2, 64);
    if (cg == 0) rinvs[w][r] = 1.f / lsum;
    float riv[4];
    #pragma unroll
    for (int i = 0; i < 4; ++i) riv[i] = rinvs[w][q * 4 + i];     // same-wave LDS read

    // stage normalized head output: cols w*64 + dt*16 + rl, rows q*4+i
    #pragma unroll
    for (int dt = 0; dt < 4; ++dt) {
        #pragma unroll
        for (int i = 0; i < 4; ++i)
            hm_stage[q * 4 + i][w * 64 + dt * 16 + rl] = __float2bfloat16(acc[dt][i] * riv[i]);
    }
    __syncthreads();

    // ---- proj: A from hm_stage (LDS), B from pwb; wave w takes col-tiles w+4j ----
    short8 paf[8];
    const __hip_bfloat16* Arow2 = &hm_stage[rl][0] + q * 8;
    #pragma unroll
    for (int k0 = 0; k0 < 8; ++k0) paf[k0] = *(const short8*)(Arow2 + k0 * 32);

    floatx4 pacc[4];
    #pragma unroll
    for (int j = 0; j < 4; ++j) {
        int ct = w + j * 4;
        const __hip_bfloat16* Brow = pwb + (size_t)(ct * 16 + rl) * 256 + q * 8;
        floatx4 a = {0.f, 0.f, 0.f, 0.f};
        #pragma unroll
        for (int k0 = 0; k0 < 8; ++k0) {
            short8 bfr = *(const short8*)(Brow + k0 * 32);
            a = __builtin_amdgcn_mfma_f32_16x16x32_bf16(paf[k0], bfr, a, 0, 0, 0);
        }
        pacc[j] = a;
    }

    // bias + residual + LayerNorm
    float ps[4] = {0.f, 0.f, 0.f, 0.f};
    #pragma unroll
    for (int j = 0; j < 4; ++j) {
        int col = (w + j * 4) * 16 + rl;
        float pb = proj_b[col];
        #pragma unroll
        for (int i = 0; i < 4; ++i) {
            float v = pacc[j][i] + pb + h[(size_t)(r0 + q * 4 + i) * 256 + col];
            pacc[j][i] = v;
            ps[i] += v;
        }
    }
    #pragma unroll
    for (int i = 0; i < 4; ++i) {
        float s = ps[i];
        #pragma unroll
        for (int off = 1; off < 16; off <<= 1) s += __shfl_xor(s, off, 64);
        ps[i] = s;
    }
    if (rl == 0) {
        for (int i = 0; i < 4; ++i) red[0][w][q * 4 + i] = ps[i];
    }
    __syncthreads();
    float mu[4];
    #pragma unroll
    for (int i = 0; i < 4; ++i) {
        int row = q * 4 + i;
        mu[i] = (red[0][0][row] + red[0][1][row] + red[0][2][row] + red[0][3][row]) * (1.f / 256.f);
    }

    float vs[4] = {0.f, 0.f, 0.f, 0.f};
    #pragma unroll
    for (int j = 0; j < 4; ++j) {
        #pragma unroll
        for (int i = 0; i < 4; ++i) { float cv = pacc[j][i] - mu[i]; vs[i] += cv * cv; }
    }
    #pragma unroll
    for (int i = 0; i < 4; ++i) {
        float s = vs[i];
        #pragma unroll
        for (int off = 1; off < 16; off <<= 1) s += __shfl_xor(s, off, 64);
        vs[i] = s;
    }
    if (rl == 0) {
        for (int i = 0; i < 4; ++i) red[1][w][q * 4 + i] = vs[i];
    }
    __syncthreads();
    float rs[4];
    #pragma unroll
    for (int i = 0; i < 4; ++i) {
        int row = q * 4 + i;
        float var = (red[1][0][row] + red[1][1][row] + red[1][2][row] + red[1][3][row]) * (1.f / 256.f);
        rs[i] = rsqrtf(var + 1e-5f);
    }
    #pragma unroll
    for (int j = 0; j < 4; ++j) {
        int col = (w + j * 4) * 16 + rl;
        float g = gamma[col], be = beta[col];
        #pragma unroll
        for (int i = 0; i < 4; ++i)
            out[(size_t)(r0 + q * 4 + i) * 256 + col] = (pacc[j][i] - mu[i]) * rs[i] * g + be;
    }
}

extern "C" void kernel_launch(void* const* d_in, const int* in_sizes, int n_in,
                              void* d_out, int out_size, void* d_ws, size_t ws_size,
                              hipStream_t stream) {
    const float* h      = (const float*)d_in[0];
    const int*   adj    = (const int*)d_in[1];
    const float* W      = (const float*)d_in[2];
    const float* a1     = (const float*)d_in[3];
    const float* a2     = (const float*)d_in[4];
    const float* proj_w = (const float*)d_in[5];
    const float* proj_b = (const float*)d_in[6];
    const float* gamma  = (const float*)d_in[7];
    const float* beta   = (const float*)d_in[8];
    float* out = (float*)d_out;

    char* ws = (char*)d_ws;
    __hip_bfloat16* WhT = (__hip_bfloat16*)ws;   ws += (size_t)32 * 64 * NN * 2;   // 4 MB
    __hip_bfloat16* pwb = (__hip_bfloat16*)ws;   ws += 256 * 256 * 2;              // 128 KB
    float* si = (float*)ws;                      ws += (size_t)32 * NN * 4;        // 128 KB
    float* sj = (float*)ws;                      ws += (size_t)32 * NN * 4;        // 128 KB
    unsigned* adjm = (unsigned*)ws;              ws += (size_t)NN * 32 * 4;        // 128 KB

    wh_kernel<<<656, 256, 0, stream>>>(h, W, a1, a2, proj_w, adj, WhT, si, sj, pwb, adjm);
    attn_proj_kernel<<<512, 256, 0, stream>>>(adjm, WhT, si, sj, pwb, h, proj_b, gamma, beta, out);
}

// Round 11
// 145.959 us; speedup vs baseline: 1.0099x; 1.0099x over previous
//
#include <hip/hip_runtime.h>
#include <hip/hip_bf16.h>

#define NN 1024

typedef __attribute__((ext_vector_type(8))) short short8;     // 8 x bf16 MFMA frag
typedef __attribute__((ext_vector_type(4))) short short4e;    // 4 x bf16 packed store
typedef __attribute__((ext_vector_type(4))) float floatx4;
typedef __attribute__((ext_vector_type(4))) int intx4;

static __device__ __forceinline__ short bfb(float x) {
    return (short)__bfloat16_as_ushort(__float2bfloat16(x));
}

// ================= K0: prep — WTb bf16 transpose, pwb bf16 cast, adj bitmask =================
// grid = 16 + 16 + 128 = 160 blocks, 256 threads.
__global__ __launch_bounds__(256) void prep_kernel(
    const float* __restrict__ W, const float* __restrict__ proj_w,
    const int* __restrict__ adj,
    __hip_bfloat16* __restrict__ WTb,    // [256 o][256 k], o = hh*64+d
    __hip_bfloat16* __restrict__ pwb,    // [256 o][256 k]
    unsigned* __restrict__ adjm)         // [1024][32]
{
    int blk = blockIdx.x, t = threadIdx.x;
    if (blk < 16) {
        int o = blk * 16 + (t >> 4);
        int hh = o >> 6, d = o & 63;
        #pragma unroll
        for (int kk = 0; kk < 16; ++kk) {
            int k = (t & 15) + 16 * kk;
            WTb[(size_t)o * 256 + k] = __float2bfloat16(W[((size_t)hh * 256 + k) * 64 + d]);
        }
    } else if (blk < 32) {
        size_t base = (size_t)(blk - 16) * 4096 + (size_t)t * 16;
        #pragma unroll
        for (int k = 0; k < 16; k += 4) {
            floatx4 v = *(const floatx4*)(proj_w + base + k);
            short4e tmp;
            #pragma unroll
            for (int j = 0; j < 4; ++j) tmp[j] = bfb(v[j]);
            *(short4e*)(pwb + base + k) = tmp;
        }
    } else {
        int n = (blk - 32) * 8 + (t >> 5);
        int wd = t & 31;
        const int* arow = adj + (size_t)n * NN + wd * 32;
        unsigned bits = 0;
        #pragma unroll
        for (int j4 = 0; j4 < 8; ++j4) {
            intx4 v = *(const intx4*)(arow + j4 * 4);
            #pragma unroll
            for (int j = 0; j < 4; ++j) if (v[j] != 0) bits |= (1u << (j4 * 4 + j));
        }
        adjm[(size_t)n * 32 + wd] = bits;
    }
}

// ================= K1: Wh GEMM (vectorized WTb B-loads, cross-tile prefetch) + si/sj =================
// grid = 512 blocks, 256 threads = 4 waves; wave w takes col-tiles ct = w + 4j.
__global__ __launch_bounds__(256) void wh_kernel(
    const float* __restrict__ h,
    const __hip_bfloat16* __restrict__ WTb,
    const float* __restrict__ a1, const float* __restrict__ a2,
    __hip_bfloat16* __restrict__ WhT,   // [B*H][64][NN] bf16
    float* __restrict__ si, float* __restrict__ sj)
{
    int t = threadIdx.x;
    int w = t >> 6, l = t & 63;
    int rl = l & 15, q = l >> 4;
    int r0 = blockIdx.x * 16;
    int bb = r0 >> 10;
    int n0 = r0 & 1023;

    __shared__ float redsi[4][4][16];   // [wave][head][row]
    __shared__ float redsj[4][4][16];

    // A-frags: A[m=rl][k=q*8+j] from h rows (f32 -> bf16 in regs)
    short8 af[8];
    const float* Arow = h + (size_t)(r0 + rl) * 256 + q * 8;
    #pragma unroll
    for (int k0 = 0; k0 < 8; ++k0) {
        floatx4 v0 = *(const floatx4*)(Arow + k0 * 32);
        floatx4 v1 = *(const floatx4*)(Arow + k0 * 32 + 4);
        short8 a;
        #pragma unroll
        for (int j = 0; j < 4; ++j) { a[j] = bfb(v0[j]); a[j + 4] = bfb(v1[j]); }
        af[k0] = a;
    }

    float a1v[4], a2v[4];
    #pragma unroll
    for (int j = 0; j < 4; ++j) {
        a1v[j] = a1[j * 64 + w * 16 + rl];
        a2v[j] = a2[j * 64 + w * 16 + rl];
    }

    // prefetch tile j=0 (ct = w)
    short8 bcur[8];
    {
        const __hip_bfloat16* B0 = WTb + (size_t)(w * 16 + rl) * 256 + q * 8;
        #pragma unroll
        for (int k0 = 0; k0 < 8; ++k0) bcur[k0] = *(const short8*)(B0 + k0 * 32);
    }

    #pragma unroll
    for (int j = 0; j < 4; ++j) {        // ct = w + 4j -> head j, d = w*16 + rl
        short8 bnxt[8];
        if (j < 3) {
            const __hip_bfloat16* Bn = WTb + (size_t)((w + (j + 1) * 4) * 16 + rl) * 256 + q * 8;
            #pragma unroll
            for (int k0 = 0; k0 < 8; ++k0) bnxt[k0] = *(const short8*)(Bn + k0 * 32);
        }

        floatx4 acc = {0.f, 0.f, 0.f, 0.f};
        #pragma unroll
        for (int k0 = 0; k0 < 8; ++k0)
            acc = __builtin_amdgcn_mfma_f32_16x16x32_bf16(af[k0], bcur[k0], acc, 0, 0, 0);

        // store WhT[bh = bb*4+j][d = w*16+rl][n = n0+q*4+i]
        short4e tmp;
        #pragma unroll
        for (int i = 0; i < 4; ++i) tmp[i] = bfb(acc[i]);
        *(short4e*)(WhT + ((size_t)(bb * 4 + j) * 64 + w * 16 + rl) * NN + n0 + q * 4) = tmp;

        // si/sj partials: reduce over this wave's 16 d's
        #pragma unroll
        for (int i = 0; i < 4; ++i) {
            float p1 = acc[i] * a1v[j];
            float p2 = acc[i] * a2v[j];
            #pragma unroll
            for (int off = 1; off < 16; off <<= 1) {
                p1 += __shfl_xor(p1, off, 64);
                p2 += __shfl_xor(p2, off, 64);
            }
            if (rl == 0) { redsi[w][j][q * 4 + i] = p1; redsj[w][j][q * 4 + i] = p2; }
        }

        #pragma unroll
        for (int z = 0; z < 8; ++z) bcur[z] = bnxt[z];
    }
    __syncthreads();

    if (w == 0) {
        int head = l >> 4, row = l & 15;
        float s = redsi[0][head][row] + redsi[1][head][row] + redsi[2][head][row] + redsi[3][head][row];
        si[(size_t)(bb * 4 + head) * NN + n0 + row] = s;
    } else if (w == 1) {
        int head = l >> 4, row = l & 15;
        float s = redsj[0][head][row] + redsj[1][head][row] + redsj[2][head][row] + redsj[3][head][row];
        sj[(size_t)(bb * 4 + head) * NN + n0 + row] = s;
    }
}

// ================= K2: fused attn (pipelined m-loop) + proj + LayerNorm =================
// grid = 512 blocks (16 token-rows), 256 threads = 4 waves; wave = head.
__global__ __launch_bounds__(256) void attn_proj_kernel(
    const unsigned* __restrict__ adjm,
    const __hip_bfloat16* __restrict__ WhT,
    const float* __restrict__ si, const float* __restrict__ sj,
    const __hip_bfloat16* __restrict__ pwb,
    const float* __restrict__ h,
    const float* __restrict__ proj_b, const float* __restrict__ gamma,
    const float* __restrict__ beta,
    float* __restrict__ out)
{
    int blk = blockIdx.x, t = threadIdx.x;
    int w = t >> 6, l = t & 63;
    int rl = l & 15, q = l >> 4;
    int b = blk >> 6, n0 = (blk & 63) * 16;
    int bh = b * 4 + w;                  // wave = head
    int r0 = blk * 16;

    __shared__ __align__(16) __hip_bfloat16 p_lds[4][16 * 136];   // per-wave p tile [16][128+8]
    __shared__ __align__(16) __hip_bfloat16 hm_stage[16][264];
    __shared__ float rinvs[4][16];
    __shared__ float red[2][4][16];

    int r = l >> 2, cg = l & 3;          // score roles: row r, m-window cg*32
    float sii = si[(size_t)bh * NN + n0 + r];
    const float* sjr = sj + (size_t)bh * NN;
    const unsigned* amrow = adjm + (size_t)(n0 + r) * 32;

    __hip_bfloat16* pt = &p_lds[w][0];
    const __hip_bfloat16* Ab = pt + rl * 136 + q * 8;
    const __hip_bfloat16* Bbase = WhT + ((size_t)bh * 64 + rl) * NN + q * 8;

    float lsum = 0.f;
    floatx4 acc[4] = { {0,0,0,0}, {0,0,0,0}, {0,0,0,0}, {0,0,0,0} };

    // score block for m-window ITX (writes p_lds, accumulates lsum)
#define SCORE_BLOCK(ITX)                                                        \
    do {                                                                        \
        int mb_ = (ITX) * 128 + cg * 32;                                        \
        unsigned bits_ = amrow[mb_ >> 5];                                       \
        short8 pv_[4];                                                          \
        _Pragma("unroll")                                                       \
        for (int c4 = 0; c4 < 8; ++c4) {                                        \
            floatx4 s4_ = *(const floatx4*)(sjr + mb_ + c4 * 4);                \
            _Pragma("unroll")                                                   \
            for (int k = 0; k < 4; ++k) {                                       \
                float x_ = sii + s4_[k];                                        \
                x_ = x_ > 0.f ? x_ : 0.2f * x_;                                 \
                x_ = ((bits_ >> (c4 * 4 + k)) & 1u) ? x_ : -1e9f;               \
                float pv = __expf(x_);                                          \
                lsum += pv;                                                     \
                pv_[c4 >> 1][(c4 & 1) * 4 + k] = bfb(pv);                       \
            }                                                                   \
        }                                                                       \
        short8* dst_ = (short8*)(pt + r * 136 + cg * 32);                       \
        dst_[0] = pv_[0]; dst_[1] = pv_[1]; dst_[2] = pv_[2]; dst_[3] = pv_[3]; \
    } while (0)

    // prologue: issue B(0) loads, then compute scores(0) under them
    short8 bcur[16];
    #pragma unroll
    for (int ks = 0; ks < 4; ++ks)
        #pragma unroll
        for (int dt = 0; dt < 4; ++dt)
            bcur[ks * 4 + dt] = *(const short8*)(Bbase + (size_t)dt * 16 * NN + ks * 32);
    SCORE_BLOCK(0);

    #pragma unroll
    for (int it = 0; it < 8; ++it) {
        short8 bnxt[16];
        if (it < 7) {                    // issue loads for it+1 BEFORE consuming bcur
            int m1 = (it + 1) * 128;
            #pragma unroll
            for (int ks = 0; ks < 4; ++ks)
                #pragma unroll
                for (int dt = 0; dt < 4; ++dt)
                    bnxt[ks * 4 + dt] = *(const short8*)(Bbase + (size_t)dt * 16 * NN + m1 + ks * 32);
        }
        // MFMA(it): A from p_lds (in-order DS ensures reads precede next writes)
        #pragma unroll
        for (int ks = 0; ks < 4; ++ks) {
            short8 afr = *(const short8*)(Ab + ks * 32);
            #pragma unroll
            for (int dt = 0; dt < 4; ++dt)
                acc[dt] = __builtin_amdgcn_mfma_f32_16x16x32_bf16(afr, bcur[ks * 4 + dt], acc[dt], 0, 0, 0);
        }
        if (it < 7) {
            SCORE_BLOCK(it + 1);         // ~650 VALU cycles blanket the bnxt latency
            #pragma unroll
            for (int z = 0; z < 16; ++z) bcur[z] = bnxt[z];
        }
    }
#undef SCORE_BLOCK

    // row sums (4 lanes share a row) -> rinv
    lsum += __shfl_xor(lsum, 1, 64);
    lsum += __shfl_xor(lsum, 2, 64);
    if (cg == 0) rinvs[w][r] = 1.f / lsum;
    float riv[4];
    #pragma unroll
    for (int i = 0; i < 4; ++i) riv[i] = rinvs[w][q * 4 + i];

    // stage normalized head output
    #pragma unroll
    for (int dt = 0; dt < 4; ++dt) {
        #pragma unroll
        for (int i = 0; i < 4; ++i)
            hm_stage[q * 4 + i][w * 64 + dt * 16 + rl] = __float2bfloat16(acc[dt][i] * riv[i]);
    }
    __syncthreads();

    // ---- proj: A from hm_stage, B from pwb; wave w takes col-tiles w+4j ----
    short8 paf[8];
    const __hip_bfloat16* Arow2 = &hm_stage[rl][0] + q * 8;
    #pragma unroll
    for (int k0 = 0; k0 < 8; ++k0) paf[k0] = *(const short8*)(Arow2 + k0 * 32);

    floatx4 pacc[4];
    #pragma unroll
    for (int j = 0; j < 4; ++j) {
        int ct = w + j * 4;
        const __hip_bfloat16* Brow = pwb + (size_t)(ct * 16 + rl) * 256 + q * 8;
        floatx4 a = {0.f, 0.f, 0.f, 0.f};
        #pragma unroll
        for (int k0 = 0; k0 < 8; ++k0) {
            short8 bfr = *(const short8*)(Brow + k0 * 32);
            a = __builtin_amdgcn_mfma_f32_16x16x32_bf16(paf[k0], bfr, a, 0, 0, 0);
        }
        pacc[j] = a;
    }

    // bias + residual + LayerNorm
    float ps[4] = {0.f, 0.f, 0.f, 0.f};
    #pragma unroll
    for (int j = 0; j < 4; ++j) {
        int col = (w + j * 4) * 16 + rl;
        float pb = proj_b[col];
        #pragma unroll
        for (int i = 0; i < 4; ++i) {
            float v = pacc[j][i] + pb + h[(size_t)(r0 + q * 4 + i) * 256 + col];
            pacc[j][i] = v;
            ps[i] += v;
        }
    }
    #pragma unroll
    for (int i = 0; i < 4; ++i) {
        float s = ps[i];
        #pragma unroll
        for (int off = 1; off < 16; off <<= 1) s += __shfl_xor(s, off, 64);
        ps[i] = s;
    }
    if (rl == 0) {
        for (int i = 0; i < 4; ++i) red[0][w][q * 4 + i] = ps[i];
    }
    __syncthreads();
    float mu[4];
    #pragma unroll
    for (int i = 0; i < 4; ++i) {
        int row = q * 4 + i;
        mu[i] = (red[0][0][row] + red[0][1][row] + red[0][2][row] + red[0][3][row]) * (1.f / 256.f);
    }

    float vs[4] = {0.f, 0.f, 0.f, 0.f};
    #pragma unroll
    for (int j = 0; j < 4; ++j) {
        #pragma unroll
        for (int i = 0; i < 4; ++i) { float cv = pacc[j][i] - mu[i]; vs[i] += cv * cv; }
    }
    #pragma unroll
    for (int i = 0; i < 4; ++i) {
        float s = vs[i];
        #pragma unroll
        for (int off = 1; off < 16; off <<= 1) s += __shfl_xor(s, off, 64);
        vs[i] = s;
    }
    if (rl == 0) {
        for (int i = 0; i < 4; ++i) red[1][w][q * 4 + i] = vs[i];
    }
    __syncthreads();
    float rs[4];
    #pragma unroll
    for (int i = 0; i < 4; ++i) {
        int row = q * 4 + i;
        float var = (red[1][0][row] + red[1][1][row] + red[1][2][row] + red[1][3][row]) * (1.f / 256.f);
        rs[i] = rsqrtf(var + 1e-5f);
    }
    #pragma unroll
    for (int j = 0; j < 4; ++j) {
        int col = (w + j * 4) * 16 + rl;
        float g = gamma[col], be = beta[col];
        #pragma unroll
        for (int i = 0; i < 4; ++i)
            out[(size_t)(r0 + q * 4 + i) * 256 + col] = (pacc[j][i] - mu[i]) * rs[i] * g + be;
    }
}

extern "C" void kernel_launch(void* const* d_in, const int* in_sizes, int n_in,
                              void* d_out, int out_size, void* d_ws, size_t ws_size,
                              hipStream_t stream) {
    const float* h      = (const float*)d_in[0];
    const int*   adj    = (const int*)d_in[1];
    const float* W      = (const float*)d_in[2];
    const float* a1     = (const float*)d_in[3];
    const float* a2     = (const float*)d_in[4];
    const float* proj_w = (const float*)d_in[5];
    const float* proj_b = (const float*)d_in[6];
    const float* gamma  = (const float*)d_in[7];
    const float* beta   = (const float*)d_in[8];
    float* out = (float*)d_out;

    char* ws = (char*)d_ws;
    __hip_bfloat16* WhT = (__hip_bfloat16*)ws;   ws += (size_t)32 * 64 * NN * 2;   // 4 MB
    __hip_bfloat16* WTb = (__hip_bfloat16*)ws;   ws += 256 * 256 * 2;              // 128 KB
    __hip_bfloat16* pwb = (__hip_bfloat16*)ws;   ws += 256 * 256 * 2;              // 128 KB
    float* si = (float*)ws;                      ws += (size_t)32 * NN * 4;        // 128 KB
    float* sj = (float*)ws;                      ws += (size_t)32 * NN * 4;        // 128 KB
    unsigned* adjm = (unsigned*)ws;              ws += (size_t)NN * 32 * 4;        // 128 KB

    prep_kernel<<<160, 256, 0, stream>>>(W, proj_w, adj, WTb, pwb, adjm);
    wh_kernel<<<512, 256, 0, stream>>>(h, WTb, a1, a2, WhT, si, sj);
    attn_proj_kernel<<<512, 256, 0, stream>>>(adjm, WhT, si, sj, pwb, h, proj_b, gamma, beta, out);
}